// Round 2
// baseline (3026.035 us; speedup 1.0000x reference)
//
#include <hip/hip_runtime.h>
#include <math.h>

#define NB   2048   // batch
#define M_   32     // model dim
#define L_   256    // sequence length (16x16)
#define DI   64     // inner dim
#define DS_  16     // state dim
#define EPSF 1e-5f

__device__ __forceinline__ float sigmf(float x){ return 1.0f/(1.0f+__expf(-x)); }
__device__ __forceinline__ float siluf(float x){ return x*sigmf(x); }
__device__ __forceinline__ float softplusf(float x){
  return fmaxf(x,0.0f) + log1pf(__expf(-fabsf(x)));
}

// ---------------- min/max reduction + fake-quant ----------------
__device__ __forceinline__ void blk_minmax(float& mn, float& mx){
  for (int off = 32; off >= 1; off >>= 1){
    mn = fminf(mn, __shfl_down(mn, off, 64));
    mx = fmaxf(mx, __shfl_down(mx, off, 64));
  }
  __shared__ float smn[4], smx[4];
  int w = threadIdx.x >> 6;
  if ((threadIdx.x & 63) == 0){ smn[w] = mn; smx[w] = mx; }
  __syncthreads();
  if (threadIdx.x == 0){
    int nw = (int)(blockDim.x >> 6);
    for (int i = 1; i < nw; ++i){ mn = fminf(mn, smn[i]); mx = fmaxf(mx, smx[i]); }
  }
}

__global__ void k_minmax_part(const float* __restrict__ t, int n, float* __restrict__ part){
  float mn = 3.402823466e38f, mx = -3.402823466e38f;
  for (int i = blockIdx.x*blockDim.x + threadIdx.x; i < n; i += gridDim.x*blockDim.x){
    float v = t[i]; mn = fminf(mn, v); mx = fmaxf(mx, v);
  }
  blk_minmax(mn, mx);
  if (threadIdx.x == 0){ part[blockIdx.x*2] = mn; part[blockIdx.x*2+1] = mx; }
}

__global__ void k_minmax_final(const float* __restrict__ part, int nparts, float* __restrict__ qp){
  float mn = 3.402823466e38f, mx = -3.402823466e38f;
  for (int i = threadIdx.x; i < nparts; i += blockDim.x){
    mn = fminf(mn, part[i*2]); mx = fmaxf(mx, part[i*2+1]);
  }
  blk_minmax(mn, mx);
  if (threadIdx.x == 0){
    qp[0] = mn; qp[1] = mx; qp[2] = (mx - mn) / 255.0f;
  }
}

__global__ void k_quant(const float* __restrict__ t, float* __restrict__ q, int n,
                        const float* __restrict__ qp){
  float mn = qp[0], mx = qp[1], step = qp[2];
  bool zero = (step == 0.0f);
  for (int i = blockIdx.x*blockDim.x + threadIdx.x; i < n; i += gridDim.x*blockDim.x){
    float v = t[i];
    float c = fminf(fmaxf(v, mn), mx);
    float r = rintf((c - mn) / (zero ? 1.0f : step));
    float o = fmaf(r, step, mn);
    q[i] = zero ? v : o;
  }
}

// ---------------- stem conv3x3 s2 + BN + SiLU ----------------
__launch_bounds__(256)
__global__ void k_stem(const float* __restrict__ x, const float* __restrict__ wq,
                       const float* __restrict__ bn_g, const float* __restrict__ bn_b,
                       const float* __restrict__ bn_m, const float* __restrict__ bn_v,
                       float* __restrict__ h){
  int b = blockIdx.x;
  __shared__ float xs[2048];   // (2,32,32)
  __shared__ float wsh[576];   // (32,2,3,3)
  const float* xb = x + (size_t)b*2048;
  for (int i = threadIdx.x; i < 2048; i += 256) xs[i] = xb[i];
  for (int i = threadIdx.x; i < 576; i += 256) wsh[i] = wq[i];
  __syncthreads();
  int l = threadIdx.x;           // one thread per output pixel
  int oy = l >> 4, ox = l & 15;
  for (int m = 0; m < M_; ++m){
    float acc = 0.f;
    #pragma unroll
    for (int c = 0; c < 2; ++c){
      #pragma unroll
      for (int ky = 0; ky < 3; ++ky){
        int iy = oy*2 - 1 + ky;
        if (iy < 0 || iy >= 32) continue;
        #pragma unroll
        for (int kx = 0; kx < 3; ++kx){
          int ix = ox*2 - 1 + kx;
          if (ix < 0 || ix >= 32) continue;
          acc += xs[c*1024 + iy*32 + ix] * wsh[((m*2 + c)*3 + ky)*3 + kx];
        }
      }
    }
    float r = (acc - bn_m[m]) * rsqrtf(bn_v[m] + EPSF) * bn_g[m] + bn_b[m];
    h[((size_t)b*M_ + m)*L_ + l] = siluf(r);
  }
}

// ---------------- fully fused mamba block ----------------
// one block per batch element; everything LDS-resident.
// LDS: hn[256][33] 33.8KB + xcs[256][65] 66.5KB + db[256][35] 35.8KB + wx[2176] 8.7KB = ~145KB
__launch_bounds__(256, 1)
__global__ void k_mamba(float* __restrict__ hio,              // (B,M,L) residual stream, RMW
                        const float* __restrict__ lng, const float* __restrict__ lnb,
                        const float* __restrict__ W_in,       // (32,128)
                        const float* __restrict__ conv_w,     // (64,4)
                        const float* __restrict__ conv_b,     // (64)
                        const float* __restrict__ W_xproj,    // (64,34)
                        const float* __restrict__ W_dt,       // (2,64)
                        const float* __restrict__ dt_bias,    // (64)
                        const float* __restrict__ A_log,      // (64,16)
                        const float* __restrict__ D_ssm,      // (64)
                        const float* __restrict__ W_out){     // (64,32)
  const int b = blockIdx.x;
  const int tid = threadIdx.x;
  __shared__ float hn[L_][M_+1];    // LN output
  __shared__ float xcs[L_][DI+1];   // xs -> conv+silu -> (scan output ys)
  __shared__ float db[L_][35];      // xproj output (34 used)
  __shared__ float wx[DI*34];       // staged W_xproj; reused for W_out in phase D
  float* hb = hio + (size_t)b*M_*L_;
  const float LOG2E = 1.44269504088896340736f;

  // stage W_xproj (used phase C)
  for (int i = tid; i < DI*34; i += 256) wx[i] = W_xproj[i];

  // ---- phase A: LayerNorm (thread = l) ----
  {
    int l = tid;
    float sr[M_];
    float s = 0.f;
    #pragma unroll
    for (int m = 0; m < M_; ++m){ sr[m] = hb[m*L_ + l]; s += sr[m]; }
    float mu = s * (1.0f/32.0f);
    float v = 0.f;
    #pragma unroll
    for (int m = 0; m < M_; ++m){ float dd = sr[m]-mu; v += dd*dd; }
    float rs = rsqrtf(v*(1.0f/32.0f) + EPSF);
    #pragma unroll
    for (int m = 0; m < M_; ++m) hn[l][m] = (sr[m]-mu)*rs*lng[m] + lnb[m];
  }
  __syncthreads();

  // ---- phase B: xs = hn @ W_in[:,:64]; causal dwconv4 + SiLU (thread = (chunk,d)) ----
  {
    int cchunk = tid >> 6;     // 0..3 -> l-range of 64
    int d = tid & 63;
    float wreg[M_];
    #pragma unroll
    for (int m = 0; m < M_; ++m) wreg[m] = W_in[m*128 + d];
    float w0 = conv_w[d*4+0], w1 = conv_w[d*4+1], w2 = conv_w[d*4+2], w3 = conv_w[d*4+3];
    float cb = conv_b[d];
    int l0 = cchunk*64;
    float xm3 = 0.f, xm2 = 0.f, xm1 = 0.f;
    #pragma unroll
    for (int p = 3; p >= 1; --p){       // redundant history across chunk boundary
      int l = l0 - p;
      float xv = 0.f;
      if (l >= 0){
        #pragma unroll
        for (int m = 0; m < M_; ++m) xv = fmaf(hn[l][m], wreg[m], xv);
      }
      xm3 = xm2; xm2 = xm1; xm1 = xv;
    }
    for (int l = l0; l < l0+64; ++l){
      float xv = 0.f;
      #pragma unroll
      for (int m = 0; m < M_; ++m) xv = fmaf(hn[l][m], wreg[m], xv);
      float a = fmaf(w0,xm3, fmaf(w1,xm2, fmaf(w2,xm1, fmaf(w3,xv,cb))));
      xcs[l][d] = siluf(a);
      xm3 = xm2; xm2 = xm1; xm1 = xv;
    }
  }
  __syncthreads();

  // ---- phase C: dbl = xc @ W_xproj (thread = l) ----
  {
    int l = tid;
    float acc[34];
    #pragma unroll
    for (int j = 0; j < 34; ++j) acc[j] = 0.f;
    for (int m = 0; m < DI; ++m){
      float xv = xcs[l][m];
      #pragma unroll
      for (int j = 0; j < 34; ++j) acc[j] = fmaf(xv, wx[m*34+j], acc[j]);
    }
    #pragma unroll
    for (int j = 0; j < 34; ++j) db[l][j] = acc[j];
  }
  __syncthreads();

  // ---- phase S: selective scan, 1024 (d,s)-recurrences over 256+(sg,d) lanes ----
  // lane = sg*16 + dlow within wave; d = wave*16 + dlow; each lane owns states sg*4..sg*4+3.
  // z-projection split over the 4 sg lanes; y and z reduced by the same xor-butterfly.
  {
    const int lane = tid & 63;
    const int w = tid >> 6;
    const int dlow = lane & 15;
    const int sg = lane >> 4;
    const int d = w*16 + dlow;
    float wdt0 = W_dt[d], wdt1 = W_dt[64+d], dtb = dt_bias[d], Dd = D_ssm[d];
    float w2r[8];
    #pragma unroll
    for (int k = 0; k < 8; ++k) w2r[k] = W_in[(sg*8+k)*128 + 64 + d];
    float A2[4], hst[4];
    #pragma unroll
    for (int j = 0; j < 4; ++j){
      A2[j] = -__expf(A_log[d*DS_ + sg*4 + j]) * LOG2E;
      hst[j] = 0.f;
    }
    for (int l = 0; l < L_; ++l){
      float r0 = db[l][0], r1 = db[l][1];
      float dtv = softplusf(fmaf(r0, wdt0, fmaf(r1, wdt1, dtb)));
      float xv = xcs[l][d];
      float zp = 0.f;
      #pragma unroll
      for (int k = 0; k < 8; ++k) zp = fmaf(hn[l][sg*8+k], w2r[k], zp);
      float dtx = dtv * xv;
      float yp = 0.f;
      #pragma unroll
      for (int j = 0; j < 4; ++j){
        float dA = exp2f(dtv * A2[j]);
        float hv = fmaf(hst[j], dA, dtx * db[l][2 + sg*4 + j]);
        hst[j] = hv;
        yp = fmaf(hv, db[l][18 + sg*4 + j], yp);
      }
      yp += __shfl_xor(yp, 16, 64);
      zp += __shfl_xor(zp, 16, 64);
      yp += __shfl_xor(yp, 32, 64);
      zp += __shfl_xor(zp, 32, 64);
      float ysf = (yp + xv*Dd) * siluf(zp);
      if (sg == 0) xcs[l][d] = ysf;   // overwrite in place (read xv happened above)
    }
  }
  __syncthreads();

  // stage W_out into wx region (W_xproj dead now)
  for (int i = tid; i < DI*M_; i += 256) wx[i] = W_out[i];
  __syncthreads();

  // ---- phase D: out = ys @ W_out; residual add (thread = l) ----
  {
    int l = tid;
    float xr[DI];
    #pragma unroll
    for (int d = 0; d < DI; ++d) xr[d] = xcs[l][d];
    #pragma unroll 4
    for (int m = 0; m < M_; ++m){
      float acc = 0.f;
      #pragma unroll
      for (int d = 0; d < DI; ++d) acc = fmaf(xr[d], wx[d*M_ + m], acc);
      hb[m*L_ + l] += acc;
    }
  }
}

// ---------------- 1x1 proj conv (quantized) + flatten ----------------
__launch_bounds__(256)
__global__ void k_proj(const float* __restrict__ h, const float* __restrict__ pw,
                       float* __restrict__ h2){
  int b = blockIdx.x;
  __shared__ float hsd[M_*L_];
  for (int i = threadIdx.x; i < M_*L_; i += 256) hsd[i] = h[(size_t)b*M_*L_ + i];
  __syncthreads();
  int l = threadIdx.x;
  #pragma unroll
  for (int c = 0; c < 8; ++c){
    float acc = 0.f;
    #pragma unroll
    for (int m = 0; m < M_; ++m) acc = fmaf(hsd[m*L_ + l], pw[c*M_ + m], acc);
    h2[(size_t)b*2048 + c*L_ + l] = acc;
  }
}

// ---------------- FC (2048->512, quantized W) + bias + sigmoid ----------------
__launch_bounds__(256)
__global__ void k_fc(const float* __restrict__ A, const float* __restrict__ W,
                     const float* __restrict__ bias, float* __restrict__ out){
  int bi = blockIdx.x, bj = blockIdx.y;
  __shared__ float As[32][68];
  __shared__ float Ws[32][68];
  int tid = threadIdx.x;
  int ti = tid >> 4, tj = tid & 15;
  float acc[4][4];
  #pragma unroll
  for (int u=0;u<4;++u){
    #pragma unroll
    for (int v=0;v<4;++v) acc[u][v]=0.f;
  }
  for (int k0 = 0; k0 < 2048; k0 += 32){
    __syncthreads();
    #pragma unroll
    for (int r8 = 0; r8 < 8; ++r8){
      int i = tid + r8*256;
      int r = i >> 5, c = i & 31;
      As[c][r] = A[(size_t)(bi*64+r)*2048 + k0 + c];
      Ws[c][r] = W[(size_t)(bj*64+r)*2048 + k0 + c];
    }
    __syncthreads();
    #pragma unroll
    for (int k = 0; k < 32; ++k){
      float4 av = *(const float4*)&As[k][ti*4];
      float4 wv = *(const float4*)&Ws[k][tj*4];
      float a4[4] = {av.x,av.y,av.z,av.w};
      float w4[4] = {wv.x,wv.y,wv.z,wv.w};
      #pragma unroll
      for (int u=0;u<4;++u){
        #pragma unroll
        for (int v=0;v<4;++v) acc[u][v] = fmaf(a4[u], w4[v], acc[u][v]);
      }
    }
  }
  #pragma unroll
  for (int u=0;u<4;++u){
    int r = bi*64 + ti*4 + u;
    #pragma unroll
    for (int v=0;v<4;++v){
      int c = bj*64 + tj*4 + v;
      out[(size_t)r*512 + c] = sigmf(acc[u][v] + bias[c]);
    }
  }
}

// ---------------- workspace layout (floats) — total ~92 MB ----------------
static const size_t OF_H    = 0;          // (B,M,L)      16777216
static const size_t OF_H2   = 16777216;   // (B,2048)      4194304
static const size_t OF_LG   = 20971520;   // (B,512)       1048576
static const size_t OF_WQF  = 22020096;   // fc_w quant    1048576
static const size_t OF_WQS  = 23068672;   // stem_w quant     1024
static const size_t OF_WQP  = 23069696;   // proj_w quant      512
static const size_t OF_PART = 23070208;   // partials          512
static const size_t OF_QP   = 23070720;   // qparams            16

extern "C" void kernel_launch(void* const* d_in, const int* in_sizes, int n_in,
                              void* d_out, int out_size, void* d_ws, size_t ws_size,
                              hipStream_t stream){
  (void)in_sizes; (void)n_in; (void)out_size; (void)ws_size;
  const float* x      = (const float*)d_in[0];
  const float* stem_w = (const float*)d_in[1];
  const float* bn_g   = (const float*)d_in[2];
  const float* bn_b   = (const float*)d_in[3];
  const float* bn_m   = (const float*)d_in[4];
  const float* bn_v   = (const float*)d_in[5];
  const float* ln_g   = (const float*)d_in[6];
  const float* ln_b   = (const float*)d_in[7];
  const float* W_in   = (const float*)d_in[8];
  const float* conv_w = (const float*)d_in[9];
  const float* conv_b = (const float*)d_in[10];
  const float* W_xp   = (const float*)d_in[11];
  const float* W_dt   = (const float*)d_in[12];
  const float* dt_b   = (const float*)d_in[13];
  const float* A_log  = (const float*)d_in[14];
  const float* D_ssm  = (const float*)d_in[15];
  const float* W_out  = (const float*)d_in[16];
  const float* proj_w = (const float*)d_in[17];
  const float* fc_w   = (const float*)d_in[18];
  const float* fc_b   = (const float*)d_in[19];
  float* ws   = (float*)d_ws;
  float* bh   = ws + OF_H;
  float* bh2  = ws + OF_H2;
  float* blg  = ws + OF_LG;
  float* wqf  = ws + OF_WQF;
  float* wqs  = ws + OF_WQS;
  float* wqp  = ws + OF_WQP;
  float* part = ws + OF_PART;
  float* qp   = ws + OF_QP;

  // quantize the three weight tensors
  k_minmax_part<<<1,256,0,stream>>>(stem_w, 576, part);
  k_minmax_final<<<1,256,0,stream>>>(part, 1, qp+0);
  k_quant<<<3,256,0,stream>>>(stem_w, wqs, 576, qp+0);

  k_minmax_part<<<1,256,0,stream>>>(proj_w, 256, part);
  k_minmax_final<<<1,256,0,stream>>>(part, 1, qp+4);
  k_quant<<<1,256,0,stream>>>(proj_w, wqp, 256, qp+4);

  k_minmax_part<<<256,256,0,stream>>>(fc_w, 1048576, part);
  k_minmax_final<<<1,256,0,stream>>>(part, 256, qp+8);
  k_quant<<<1024,256,0,stream>>>(fc_w, wqf, 1048576, qp+8);

  // stem
  k_stem<<<NB,256,0,stream>>>(x, wqs, bn_g, bn_b, bn_m, bn_v, bh);

  // 2 fused mamba blocks
  for (int i = 0; i < 2; ++i){
    k_mamba<<<NB,256,0,stream>>>(bh, ln_g+i*32, ln_b+i*32, W_in+i*4096,
                                 conv_w+i*256, conv_b+i*64, W_xp+i*2176,
                                 W_dt+i*128, dt_b+i*64, A_log+i*1024,
                                 D_ssm+i*64, W_out+i*2048);
  }

  // head
  k_proj<<<NB,256,0,stream>>>(bh, wqp, bh2);
  dim3 fcg(32, 8);
  k_fc<<<fcg,256,0,stream>>>(bh2, wqf, fc_b, blg);

  // output fake-quant (global min/max over all 1M outputs)
  k_minmax_part<<<256,256,0,stream>>>(blg, 1048576, part);
  k_minmax_final<<<1,256,0,stream>>>(part, 256, qp+12);
  k_quant<<<1024,256,0,stream>>>(blg, (float*)d_out, 1048576, qp+12);
}

// Round 3
// 2738.851 us; speedup vs baseline: 1.1049x; 1.1049x over previous
//
#include <hip/hip_runtime.h>
#include <math.h>

#define NB   2048   // batch
#define M_   32     // model dim
#define L_   256    // sequence length (16x16)
#define DI   64     // inner dim
#define DS_  16     // state dim
#define EPSF 1e-5f

__device__ __forceinline__ float sigmf(float x){ return 1.0f/(1.0f+__expf(-x)); }
__device__ __forceinline__ float siluf(float x){ return x*sigmf(x); }
__device__ __forceinline__ float softplusf(float x){
  return fmaxf(x,0.0f) + log1pf(__expf(-fabsf(x)));
}

// ---------------- min/max reduction + fake-quant ----------------
__device__ __forceinline__ void blk_minmax(float& mn, float& mx){
  for (int off = 32; off >= 1; off >>= 1){
    mn = fminf(mn, __shfl_down(mn, off, 64));
    mx = fmaxf(mx, __shfl_down(mx, off, 64));
  }
  __shared__ float smn[4], smx[4];
  int w = threadIdx.x >> 6;
  if ((threadIdx.x & 63) == 0){ smn[w] = mn; smx[w] = mx; }
  __syncthreads();
  if (threadIdx.x == 0){
    int nw = (int)(blockDim.x >> 6);
    for (int i = 1; i < nw; ++i){ mn = fminf(mn, smn[i]); mx = fmaxf(mx, smx[i]); }
  }
}

__global__ void k_minmax_part(const float* __restrict__ t, int n, float* __restrict__ part){
  float mn = 3.402823466e38f, mx = -3.402823466e38f;
  for (int i = blockIdx.x*blockDim.x + threadIdx.x; i < n; i += gridDim.x*blockDim.x){
    float v = t[i]; mn = fminf(mn, v); mx = fmaxf(mx, v);
  }
  blk_minmax(mn, mx);
  if (threadIdx.x == 0){ part[blockIdx.x*2] = mn; part[blockIdx.x*2+1] = mx; }
}

__global__ void k_minmax_final(const float* __restrict__ part, int nparts, float* __restrict__ qp){
  float mn = 3.402823466e38f, mx = -3.402823466e38f;
  for (int i = threadIdx.x; i < nparts; i += blockDim.x){
    mn = fminf(mn, part[i*2]); mx = fmaxf(mx, part[i*2+1]);
  }
  blk_minmax(mn, mx);
  if (threadIdx.x == 0){
    qp[0] = mn; qp[1] = mx; qp[2] = (mx - mn) / 255.0f;
  }
}

__global__ void k_quant(const float* __restrict__ t, float* __restrict__ q, int n,
                        const float* __restrict__ qp){
  float mn = qp[0], mx = qp[1], step = qp[2];
  bool zero = (step == 0.0f);
  for (int i = blockIdx.x*blockDim.x + threadIdx.x; i < n; i += gridDim.x*blockDim.x){
    float v = t[i];
    float c = fminf(fmaxf(v, mn), mx);
    float r = rintf((c - mn) / (zero ? 1.0f : step));
    float o = fmaf(r, step, mn);
    q[i] = zero ? v : o;
  }
}

// ---------------- stem conv3x3 s2 + BN + SiLU ----------------
// weights/bn via wave-uniform scalar loads; only input image staged in LDS
__launch_bounds__(256)
__global__ void k_stem(const float* __restrict__ x, const float* __restrict__ wq,
                       const float* __restrict__ bn_g, const float* __restrict__ bn_b,
                       const float* __restrict__ bn_m, const float* __restrict__ bn_v,
                       float* __restrict__ h){
  int b = blockIdx.x;
  __shared__ float xs[2048];   // (2,32,32)
  const float* xb = x + (size_t)b*2048;
  for (int i = threadIdx.x; i < 2048; i += 256) xs[i] = xb[i];
  __syncthreads();
  int l = threadIdx.x;           // one thread per output pixel
  int oy = l >> 4, ox = l & 15;
  for (int m = 0; m < M_; ++m){
    float acc = 0.f;
    #pragma unroll
    for (int c = 0; c < 2; ++c){
      #pragma unroll
      for (int ky = 0; ky < 3; ++ky){
        int iy = oy*2 - 1 + ky;
        if (iy < 0 || iy >= 32) continue;
        #pragma unroll
        for (int kx = 0; kx < 3; ++kx){
          int ix = ox*2 - 1 + kx;
          if (ix < 0 || ix >= 32) continue;
          acc = fmaf(xs[c*1024 + iy*32 + ix], wq[((m*2 + c)*3 + ky)*3 + kx], acc);
        }
      }
    }
    float r = (acc - bn_m[m]) * rsqrtf(bn_v[m] + EPSF) * bn_g[m] + bn_b[m];
    h[((size_t)b*M_ + m)*L_ + l] = siluf(r);
  }
}

// ---------------- fully fused mamba block (v2: scalar-load weights) ----------------
// one block per batch element; activations LDS-resident, weights via s_load.
// LDS: hn[256][36] 36.9KB + xcs[256][68] 69.6KB + db[256][36] 36.9KB = 143.4KB
__launch_bounds__(256, 1)
__global__ void k_mamba(float* __restrict__ hio,              // (B,M,L) residual stream, RMW
                        const float* __restrict__ lng, const float* __restrict__ lnb,
                        const float* __restrict__ W_in,       // (32,128)
                        const float* __restrict__ conv_w,     // (64,4)
                        const float* __restrict__ conv_b,     // (64)
                        const float* __restrict__ W_xproj,    // (64,34)
                        const float* __restrict__ W_dt,       // (2,64)
                        const float* __restrict__ dt_bias,    // (64)
                        const float* __restrict__ A_log,      // (64,16)
                        const float* __restrict__ D_ssm,      // (64)
                        const float* __restrict__ W_out){     // (64,32)
  const int b = blockIdx.x;
  const int tid = threadIdx.x;
  __shared__ float hn[L_][36];    // LN output (stride 144B: 16B aligned rows)
  __shared__ float xcs[L_][68];   // xs -> conv+silu -> y_raw -> (unused after D)
  __shared__ float db[L_][36];    // xproj out; cols: dt 0..1, B 4..19, C 20..35
  float* hb = hio + (size_t)b*M_*L_;
  const float LOG2E = 1.44269504088896340736f;

  // ---- phase A: LayerNorm (thread = l) ----
  {
    int l = tid;
    float sr[M_];
    float s = 0.f;
    #pragma unroll
    for (int m = 0; m < M_; ++m){ sr[m] = hb[m*L_ + l]; s += sr[m]; }
    float mu = s * (1.0f/32.0f);
    float v = 0.f;
    #pragma unroll
    for (int m = 0; m < M_; ++m){ float dd = sr[m]-mu; v += dd*dd; }
    float rs = rsqrtf(v*(1.0f/32.0f) + EPSF);
    #pragma unroll
    for (int m4 = 0; m4 < 8; ++m4){
      float4 o;
      o.x = (sr[m4*4+0]-mu)*rs*lng[m4*4+0] + lnb[m4*4+0];
      o.y = (sr[m4*4+1]-mu)*rs*lng[m4*4+1] + lnb[m4*4+1];
      o.z = (sr[m4*4+2]-mu)*rs*lng[m4*4+2] + lnb[m4*4+2];
      o.w = (sr[m4*4+3]-mu)*rs*lng[m4*4+3] + lnb[m4*4+3];
      *(float4*)&hn[l][m4*4] = o;
    }
  }
  __syncthreads();

  // ---- phase B1: xs = hn @ W_in[:,:64] (thread = l; W via uniform s_load) ----
  {
    int l = tid;
    float acc[DI];
    #pragma unroll
    for (int d = 0; d < DI; ++d) acc[d] = 0.f;
    for (int m4 = 0; m4 < 8; ++m4){
      float4 h4 = *(const float4*)&hn[l][m4*4];
      float hv[4] = {h4.x, h4.y, h4.z, h4.w};
      #pragma unroll
      for (int k = 0; k < 4; ++k){
        const float* wr = W_in + (m4*4+k)*128;   // uniform row -> s_load
        #pragma unroll
        for (int d = 0; d < DI; ++d) acc[d] = fmaf(hv[k], wr[d], acc[d]);
      }
    }
    #pragma unroll
    for (int d4 = 0; d4 < 16; ++d4)
      *(float4*)&xcs[l][d4*4] = make_float4(acc[d4*4],acc[d4*4+1],acc[d4*4+2],acc[d4*4+3]);
  }
  __syncthreads();

  // ---- phase B2: causal dwconv4 + SiLU, in-place on xcs (thread = (chunk,d)) ----
  {
    const int ch = tid >> 6, d = tid & 63;
    const int l0 = ch*64;
    float c0 = conv_w[d*4+0], c1 = conv_w[d*4+1], c2 = conv_w[d*4+2], c3 = conv_w[d*4+3];
    float cb = conv_b[d];
    // prologue: read boundary history (other chunk's rows) before anyone overwrites
    float xm3 = (l0>=3) ? xcs[l0-3][d] : 0.f;
    float xm2 = (l0>=2) ? xcs[l0-2][d] : 0.f;
    float xm1 = (l0>=1) ? xcs[l0-1][d] : 0.f;
    __syncthreads();
    for (int i = 0; i < 64; ++i){
      int l = l0 + i;
      float xv = xcs[l][d];
      float a = fmaf(c0,xm3, fmaf(c1,xm2, fmaf(c2,xm1, fmaf(c3,xv,cb))));
      xcs[l][d] = siluf(a);
      xm3 = xm2; xm2 = xm1; xm1 = xv;
    }
  }
  __syncthreads();

  // ---- phase C: dbl = xc @ W_xproj (thread = l; W via uniform s_load) ----
  {
    int l = tid;
    float acc[34];
    #pragma unroll
    for (int j = 0; j < 34; ++j) acc[j] = 0.f;
    for (int m4 = 0; m4 < 16; ++m4){
      float4 x4 = *(const float4*)&xcs[l][m4*4];
      float xv[4] = {x4.x, x4.y, x4.z, x4.w};
      #pragma unroll
      for (int k = 0; k < 4; ++k){
        const float* wr = W_xproj + (m4*4+k)*34;  // uniform -> s_load
        #pragma unroll
        for (int j = 0; j < 34; ++j) acc[j] = fmaf(xv[k], wr[j], acc[j]);
      }
    }
    *(float2*)&db[l][0]  = make_float2(acc[0], acc[1]);                      // dt
    #pragma unroll
    for (int q = 0; q < 4; ++q)                                              // B -> cols 4..19
      *(float4*)&db[l][4+q*4]  = make_float4(acc[2+q*4],acc[3+q*4],acc[4+q*4],acc[5+q*4]);
    #pragma unroll
    for (int q = 0; q < 4; ++q)                                              // C -> cols 20..35
      *(float4*)&db[l][20+q*4] = make_float4(acc[18+q*4],acc[19+q*4],acc[20+q*4],acc[21+q*4]);
  }
  __syncthreads();

  // ---- phase S: selective scan (lane = sg*16+dlow, d = wave*16+dlow, 4 states/lane) ----
  {
    const int lane = tid & 63;
    const int w = tid >> 6;
    const int dlow = lane & 15;
    const int sg = lane >> 4;
    const int d = w*16 + dlow;
    float wdt0 = W_dt[d], wdt1 = W_dt[64+d], dtb = dt_bias[d], Dd = D_ssm[d];
    float A2[4], hst[4];
    #pragma unroll
    for (int j = 0; j < 4; ++j){
      A2[j] = -__expf(A_log[d*DS_ + sg*4 + j]) * LOG2E;
      hst[j] = 0.f;
    }
    for (int l = 0; l < L_; ++l){
      float2 r01 = *(const float2*)&db[l][0];                 // broadcast b64
      float dtv = softplusf(fmaf(r01.x, wdt0, fmaf(r01.y, wdt1, dtb)));
      float xv = xcs[l][d];
      float dtx = dtv * xv;
      float4 Bv = *(const float4*)&db[l][4  + sg*4];          // b128
      float4 Cv = *(const float4*)&db[l][20 + sg*4];          // b128
      float Ba[4] = {Bv.x,Bv.y,Bv.z,Bv.w};
      float Ca[4] = {Cv.x,Cv.y,Cv.z,Cv.w};
      float yp = 0.f;
      #pragma unroll
      for (int j = 0; j < 4; ++j){
        float dA = exp2f(dtv * A2[j]);
        float hv = fmaf(hst[j], dA, dtx * Ba[j]);
        hst[j] = hv;
        yp = fmaf(hv, Ca[j], yp);
      }
      yp += __shfl_xor(yp, 16, 64);
      yp += __shfl_xor(yp, 32, 64);
      if (sg == 0) xcs[l][d] = fmaf(xv, Dd, yp);   // y_raw = y + x*D (gate applied in D)
    }
  }
  __syncthreads();

  // ---- phase D: z-proj + gate + out-proj + residual (thread = l; W uniform s_load) ----
  {
    int l = tid;
    float z[DI];
    #pragma unroll
    for (int d = 0; d < DI; ++d) z[d] = 0.f;
    for (int m4 = 0; m4 < 8; ++m4){
      float4 h4 = *(const float4*)&hn[l][m4*4];
      float hv[4] = {h4.x, h4.y, h4.z, h4.w};
      #pragma unroll
      for (int k = 0; k < 4; ++k){
        const float* wr = W_in + (m4*4+k)*128 + 64;  // z-columns, uniform -> s_load
        #pragma unroll
        for (int d = 0; d < DI; ++d) z[d] = fmaf(hv[k], wr[d], z[d]);
      }
    }
    float acc[M_];
    #pragma unroll
    for (int m = 0; m < M_; ++m) acc[m] = 0.f;
    for (int d4 = 0; d4 < 16; ++d4){
      float4 y4 = *(const float4*)&xcs[l][d4*4];
      float g[4];
      g[0] = y4.x * siluf(z[d4*4+0]);
      g[1] = y4.y * siluf(z[d4*4+1]);
      g[2] = y4.z * siluf(z[d4*4+2]);
      g[3] = y4.w * siluf(z[d4*4+3]);
      #pragma unroll
      for (int k = 0; k < 4; ++k){
        const float* wr = W_out + (d4*4+k)*32;       // uniform -> s_load
        #pragma unroll
        for (int m = 0; m < M_; ++m) acc[m] = fmaf(g[k], wr[m], acc[m]);
      }
    }
    #pragma unroll
    for (int m = 0; m < M_; ++m) hb[m*L_ + l] += acc[m];
  }
}

// ---------------- 1x1 proj conv (quantized) + flatten ----------------
__launch_bounds__(256)
__global__ void k_proj(const float* __restrict__ h, const float* __restrict__ pw,
                       float* __restrict__ h2){
  int b = blockIdx.x;
  __shared__ float hsd[M_*L_];
  for (int i = threadIdx.x; i < M_*L_; i += 256) hsd[i] = h[(size_t)b*M_*L_ + i];
  __syncthreads();
  int l = threadIdx.x;
  #pragma unroll
  for (int c = 0; c < 8; ++c){
    float acc = 0.f;
    #pragma unroll
    for (int m = 0; m < M_; ++m) acc = fmaf(hsd[m*L_ + l], pw[c*M_ + m], acc);
    h2[(size_t)b*2048 + c*L_ + l] = acc;
  }
}

// ---------------- FC (2048->512, quantized W) + bias + sigmoid ----------------
__launch_bounds__(256)
__global__ void k_fc(const float* __restrict__ A, const float* __restrict__ W,
                     const float* __restrict__ bias, float* __restrict__ out){
  int bi = blockIdx.x, bj = blockIdx.y;
  __shared__ float As[32][68];
  __shared__ float Ws[32][68];
  int tid = threadIdx.x;
  int ti = tid >> 4, tj = tid & 15;
  float acc[4][4];
  #pragma unroll
  for (int u=0;u<4;++u){
    #pragma unroll
    for (int v=0;v<4;++v) acc[u][v]=0.f;
  }
  for (int k0 = 0; k0 < 2048; k0 += 32){
    __syncthreads();
    #pragma unroll
    for (int r8 = 0; r8 < 8; ++r8){
      int i = tid + r8*256;
      int r = i >> 5, c = i & 31;
      As[c][r] = A[(size_t)(bi*64+r)*2048 + k0 + c];
      Ws[c][r] = W[(size_t)(bj*64+r)*2048 + k0 + c];
    }
    __syncthreads();
    #pragma unroll
    for (int k = 0; k < 32; ++k){
      float4 av = *(const float4*)&As[k][ti*4];
      float4 wv = *(const float4*)&Ws[k][tj*4];
      float a4[4] = {av.x,av.y,av.z,av.w};
      float w4[4] = {wv.x,wv.y,wv.z,wv.w};
      #pragma unroll
      for (int u=0;u<4;++u){
        #pragma unroll
        for (int v=0;v<4;++v) acc[u][v] = fmaf(a4[u], w4[v], acc[u][v]);
      }
    }
  }
  #pragma unroll
  for (int u=0;u<4;++u){
    int r = bi*64 + ti*4 + u;
    #pragma unroll
    for (int v=0;v<4;++v){
      int c = bj*64 + tj*4 + v;
      out[(size_t)r*512 + c] = sigmf(acc[u][v] + bias[c]);
    }
  }
}

// ---------------- workspace layout (floats) — total ~92 MB ----------------
static const size_t OF_H    = 0;          // (B,M,L)      16777216
static const size_t OF_H2   = 16777216;   // (B,2048)      4194304
static const size_t OF_LG   = 20971520;   // (B,512)       1048576
static const size_t OF_WQF  = 22020096;   // fc_w quant    1048576
static const size_t OF_WQS  = 23068672;   // stem_w quant     1024
static const size_t OF_WQP  = 23069696;   // proj_w quant      512
static const size_t OF_PART = 23070208;   // partials          512
static const size_t OF_QP   = 23070720;   // qparams            16

extern "C" void kernel_launch(void* const* d_in, const int* in_sizes, int n_in,
                              void* d_out, int out_size, void* d_ws, size_t ws_size,
                              hipStream_t stream){
  (void)in_sizes; (void)n_in; (void)out_size; (void)ws_size;
  const float* x      = (const float*)d_in[0];
  const float* stem_w = (const float*)d_in[1];
  const float* bn_g   = (const float*)d_in[2];
  const float* bn_b   = (const float*)d_in[3];
  const float* bn_m   = (const float*)d_in[4];
  const float* bn_v   = (const float*)d_in[5];
  const float* ln_g   = (const float*)d_in[6];
  const float* ln_b   = (const float*)d_in[7];
  const float* W_in   = (const float*)d_in[8];
  const float* conv_w = (const float*)d_in[9];
  const float* conv_b = (const float*)d_in[10];
  const float* W_xp   = (const float*)d_in[11];
  const float* W_dt   = (const float*)d_in[12];
  const float* dt_b   = (const float*)d_in[13];
  const float* A_log  = (const float*)d_in[14];
  const float* D_ssm  = (const float*)d_in[15];
  const float* W_out  = (const float*)d_in[16];
  const float* proj_w = (const float*)d_in[17];
  const float* fc_w   = (const float*)d_in[18];
  const float* fc_b   = (const float*)d_in[19];
  float* ws   = (float*)d_ws;
  float* bh   = ws + OF_H;
  float* bh2  = ws + OF_H2;
  float* blg  = ws + OF_LG;
  float* wqf  = ws + OF_WQF;
  float* wqs  = ws + OF_WQS;
  float* wqp  = ws + OF_WQP;
  float* part = ws + OF_PART;
  float* qp   = ws + OF_QP;

  // quantize the three weight tensors
  k_minmax_part<<<1,256,0,stream>>>(stem_w, 576, part);
  k_minmax_final<<<1,256,0,stream>>>(part, 1, qp+0);
  k_quant<<<3,256,0,stream>>>(stem_w, wqs, 576, qp+0);

  k_minmax_part<<<1,256,0,stream>>>(proj_w, 256, part);
  k_minmax_final<<<1,256,0,stream>>>(part, 1, qp+4);
  k_quant<<<1,256,0,stream>>>(proj_w, wqp, 256, qp+4);

  k_minmax_part<<<256,256,0,stream>>>(fc_w, 1048576, part);
  k_minmax_final<<<1,256,0,stream>>>(part, 256, qp+8);
  k_quant<<<1024,256,0,stream>>>(fc_w, wqf, 1048576, qp+8);

  // stem
  k_stem<<<NB,256,0,stream>>>(x, wqs, bn_g, bn_b, bn_m, bn_v, bh);

  // 2 fused mamba blocks
  for (int i = 0; i < 2; ++i){
    k_mamba<<<NB,256,0,stream>>>(bh, ln_g+i*32, ln_b+i*32, W_in+i*4096,
                                 conv_w+i*256, conv_b+i*64, W_xp+i*2176,
                                 W_dt+i*128, dt_b+i*64, A_log+i*1024,
                                 D_ssm+i*64, W_out+i*2048);
  }

  // head
  k_proj<<<NB,256,0,stream>>>(bh, wqp, bh2);
  dim3 fcg(32, 8);
  k_fc<<<fcg,256,0,stream>>>(bh2, wqf, fc_b, blg);

  // output fake-quant (global min/max over all 1M outputs)
  k_minmax_part<<<256,256,0,stream>>>(blg, 1048576, part);
  k_minmax_final<<<1,256,0,stream>>>(part, 256, qp+12);
  k_quant<<<1024,256,0,stream>>>(blg, (float*)d_out, 1048576, qp+12);
}